// Round 1
// baseline (1082.639 us; speedup 1.0000x reference)
//
#include <hip/hip_runtime.h>

// ElasticityNet fused MLP for MI355X (gfx950).
// 16-layer MLP, hidden=128, N=1048576 points, all fp32 I/O.
// Strategy: fully-fused per-workgroup MLP. Activations live in LDS for all
// layers. fp16 MFMA (16x16x32) with weights split W = Whi + Wlo (two fp16
// products, fp32 accum) => ~1e-4 abs error vs 1.875e-3 threshold.

typedef _Float16 half8 __attribute__((ext_vector_type(8)));
typedef float floatx4 __attribute__((ext_vector_type(4)));

#define NLAYER 15
#define BM 256            // rows (points) per workgroup
#define NTHREADS 512      // 8 waves

// Packed weight layout in d_ws (fp16 elements):
//   [L(15)][kh(2)][prod(2: hi,lo)][kf(2)][nf(8)][lane(64)][elem(8)]
// chunk (L,kh) = 16384 fp16 = 32 KB, contiguous.
// B-fragment mapping for mfma_f32_16x16x32_f16:
//   lane holds col = lane&15, k = kbase + 8*(lane>>4) + elem.

__global__ void pack_weights(const float* __restrict__ Ws, _Float16* __restrict__ wpk) {
    int idx = blockIdx.x * 256 + threadIdx.x;   // one per (L,k,n)
    if (idx >= NLAYER * 128 * 128) return;
    int L = idx >> 14;
    int k = (idx >> 7) & 127;
    int n = idx & 127;
    float w = Ws[((size_t)L * 128 + k) * 128 + n];
    _Float16 hi = (_Float16)w;
    _Float16 lo = (_Float16)(w - (float)hi);
    int kh   = k >> 6;
    int kf   = (k >> 5) & 1;
    int lane = ((k >> 3) & 3) * 16 + (n & 15);
    int elem = k & 7;
    int nf   = n >> 4;
    // base index with prod=0; prod stride = 2(kf)*8(nf)*64*8 = 8192 elems
    size_t base = (((((size_t)(L * 2 + kh) * 2 + 0) * 2 + kf) * 8 + nf) * 64 + lane) * 8 + elem;
    wpk[base]        = hi;
    wpk[base + 8192] = lo;
}

// Activation LDS addressing: act[row][col] fp16, row stride 256 B,
// byte = row*256 + ((col*2) ^ ((row&7)<<4))   (16B-chunk XOR swizzle)
__device__ __forceinline__ int act_byte(int row, int colbytes) {
    return row * 256 + (colbytes ^ ((row & 7) << 4));
}

__global__ __launch_bounds__(NTHREADS, 2) void mlp_fused(
    const float* __restrict__ x,   const float* __restrict__ W1,
    const float* __restrict__ b1,  const float* __restrict__ bs,
    const float* __restrict__ W17, const float* __restrict__ b17,
    const _Float16* __restrict__ wpk, float* __restrict__ out)
{
    __shared__ __align__(16) _Float16 act[BM * 128];        // 64 KB, swizzled
    __shared__ __align__(16) _Float16 wbuf[2][16384];       // 2 x 32 KB ping-pong

    const int tid  = threadIdx.x;
    const int lane = tid & 63;
    const int wid  = tid >> 6;        // 0..7
    const int wm   = wid >> 1;        // 0..3 -> rows [wm*64, wm*64+64)
    const int wn   = wid & 1;         // 0..1 -> cols [wn*64, wn*64+64)
    const int l15  = lane & 15;
    const int l4   = lane >> 4;       // 0..3
    const size_t rowbase = (size_t)blockIdx.x * BM;

    // ---- stage helper: 32KB chunk -> wbuf[buf] via global_load_lds(16B) ----
    auto stage = [&](int chunk, int buf) {
        const _Float16* src = wpk + (size_t)chunk * 16384;
#pragma unroll
        for (int i = 0; i < 4; ++i) {
            int off = (i * 8 + wid) * 512;   // fp16 elems; 1 KB per wave-issue
            __builtin_amdgcn_global_load_lds(
                (const __attribute__((address_space(1))) void*)(src + off + lane * 8),
                (__attribute__((address_space(3))) void*)(&wbuf[buf][off]),
                16, 0, 0);
        }
    };

    // issue stage of chunk 0 first so it overlaps fc1
    stage(0, 0);

    // ---- fc1: h = relu(x @ W1 + b1) -> act (fp16, swizzled) ----
    {
        int r = tid >> 1;          // 0..255
        int h = tid & 1;           // col half
        size_t grow = rowbase + r;
        float x0 = x[grow * 2 + 0];
        float x1 = x[grow * 2 + 1];
#pragma unroll 8
        for (int j = 0; j < 64; ++j) {
            int c = h * 64 + j;
            float v = fmaf(x0, W1[c], fmaf(x1, W1[128 + c], b1[c]));
            v = fmaxf(v, 0.0f);
            *(_Float16*)((char*)act + act_byte(r, c * 2)) = (_Float16)v;
        }
    }
    __syncthreads();   // fc1 done + chunk 0 staged (syncthreads drains vmcnt)

    floatx4 acc[4][4];     // [mf][nf]
    half8   afrag[4][4];   // [mf][kf], loaded once per layer (all K)

    int cur = 0;
    for (int L = 0; L < NLAYER; ++L) {
#pragma unroll
        for (int kh = 0; kh < 2; ++kh) {
            const int chunk = L * 2 + kh;
            // prefetch next chunk into the other buffer
            if (chunk + 1 < 2 * NLAYER) stage(chunk + 1, cur ^ 1);

            if (kh == 0) {
                // load ALL A-fragments for this layer (rows wm*64.., full K)
#pragma unroll
                for (int mf = 0; mf < 4; ++mf) {
                    int r = wm * 64 + mf * 16 + l15;
                    int rterm = r * 256;
                    int swz = (r & 7) << 4;
#pragma unroll
                    for (int kf = 0; kf < 4; ++kf) {
                        int byteoff = rterm + ((kf * 64 + l4 * 16) ^ swz);
                        afrag[mf][kf] = *(const half8*)((const char*)act + byteoff);
                    }
                }
#pragma unroll
                for (int mf = 0; mf < 4; ++mf)
#pragma unroll
                    for (int nf = 0; nf < 4; ++nf)
#pragma unroll
                        for (int e = 0; e < 4; ++e) acc[mf][nf][e] = 0.0f;
            }

            // MFMA over this chunk's two K-fragments, 2 products (hi, lo)
#pragma unroll
            for (int nf = 0; nf < 4; ++nf) {
                const int nfg = wn * 4 + nf;
#pragma unroll
                for (int kfl = 0; kfl < 2; ++kfl) {
                    const int kf = kh * 2 + kfl;
                    const half8 bhi = *(const half8*)&wbuf[cur][(((0 * 2 + kfl) * 8 + nfg) * 64 + lane) * 8];
                    const half8 blo = *(const half8*)&wbuf[cur][(((1 * 2 + kfl) * 8 + nfg) * 64 + lane) * 8];
#pragma unroll
                    for (int mf = 0; mf < 4; ++mf) {
                        acc[mf][nf] = __builtin_amdgcn_mfma_f32_16x16x32_f16(afrag[mf][kf], bhi, acc[mf][nf], 0, 0, 0);
                        acc[mf][nf] = __builtin_amdgcn_mfma_f32_16x16x32_f16(afrag[mf][kf], blo, acc[mf][nf], 0, 0, 0);
                    }
                }
            }

            if (kh == 1) {
                // bias + relu + fp16 store back to act
                // C layout: row = 4*(lane>>4)+reg (+16*mf+64*wm), col = lane&15 (+16*nf+64*wn)
#pragma unroll
                for (int nf = 0; nf < 4; ++nf) {
                    int col = wn * 64 + nf * 16 + l15;
                    float bv = bs[L * 128 + col];
#pragma unroll
                    for (int mf = 0; mf < 4; ++mf) {
                        int rb = wm * 64 + mf * 16 + l4 * 4;
#pragma unroll
                        for (int rg = 0; rg < 4; ++rg) {
                            int row = rb + rg;
                            float v = fmaxf(acc[mf][nf][rg] + bv, 0.0f);
                            *(_Float16*)((char*)act + act_byte(row, col * 2)) = (_Float16)v;
                        }
                    }
                }
            }
            __syncthreads();
            cur ^= 1;
        }
    }

    // ---- fc17: out = act @ W17 + b17 (fp32 dot on VALU) ----
    {
        int r = tid >> 1;
        int h = tid & 1;
        float sum = 0.0f;
        int swz = (r & 7) << 4;
#pragma unroll
        for (int c8 = 0; c8 < 8; ++c8) {
            int byteoff = r * 256 + ((h * 128 + c8 * 16) ^ swz);
            half8 v = *(const half8*)((const char*)act + byteoff);
#pragma unroll
            for (int e = 0; e < 8; ++e)
                sum = fmaf((float)v[e], W17[h * 64 + c8 * 8 + e], sum);
        }
        sum += __shfl_xor(sum, 1);
        if (h == 0) out[rowbase + r] = sum + b17[0];
    }
}

extern "C" void kernel_launch(void* const* d_in, const int* in_sizes, int n_in,
                              void* d_out, int out_size, void* d_ws, size_t ws_size,
                              hipStream_t stream) {
    const float* x   = (const float*)d_in[0];
    const float* W1  = (const float*)d_in[1];
    const float* b1  = (const float*)d_in[2];
    const float* Ws  = (const float*)d_in[3];
    const float* bs  = (const float*)d_in[4];
    const float* W17 = (const float*)d_in[5];
    const float* b17 = (const float*)d_in[6];
    float* out = (float*)d_out;
    _Float16* wpk = (_Float16*)d_ws;   // needs 983 KB

    pack_weights<<<960, 256, 0, stream>>>(Ws, wpk);
    mlp_fused<<<(1048576 / BM), NTHREADS, 0, stream>>>(x, W1, b1, bs, W17, b17, wpk, out);
}

// Round 3
// 492.128 us; speedup vs baseline: 2.1999x; 2.1999x over previous
//
#include <hip/hip_runtime.h>

// ElasticityNet fused MLP, v2: register-resident activations.
// Each wave owns 64 points through all 16 layers. Weight-only LDS staging
// (32KB/layer, double-buffered). mfma_f32_32x32x16_f16, single fp16 weights.
//
// Slot permutation sigma: contraction slot (kf, l5, e) <-> neuron
//   n = (kf>>1)*32 + (((kf&1)<<1)|(e>>2))*8 + l5*4 + (e&3)
// chosen so D-fragment (col=lane&31 -> point, row=(reg&3)+8*(reg>>2)+4*(lane>>5)
// -> neuron) maps LANE-LOCALLY onto the next layer's B-fragment:
//   kf = 2*mN + (q>>1), e = ((q&1)<<2)|r   for n = mN*32 + q*8 + (lane>>5)*4 + r.
// Both A (weights, packed by pack_weights) and B (acts) use the same sigma, so
// any internal HW k-order is consistent between operands.

typedef _Float16 half8 __attribute__((ext_vector_type(8)));
typedef float floatx2 __attribute__((ext_vector_type(2)));
typedef float floatx4 __attribute__((ext_vector_type(4)));
typedef float floatx16 __attribute__((ext_vector_type(16)));

#define NLAYER 15

// wpk layout (fp16): [L(15)][mN(4)][kf(8)][lane(64)][e(8)]  -> 32KB per layer
__global__ void pack_weights(const float* __restrict__ Ws, _Float16* __restrict__ wpk) {
    int idx = blockIdx.x * 256 + threadIdx.x;   // (L, k_in, n_out)
    if (idx >= NLAYER * 128 * 128) return;
    int L = idx >> 14;
    int k = (idx >> 7) & 127;   // input neuron (contracted)
    int n = idx & 127;          // output neuron
    float w = Ws[((size_t)L * 128 + k) * 128 + n];
    int a  = k >> 5;
    int qq = (k >> 3) & 3;
    int ll = (k >> 2) & 1;      // lane high bit (l>>5) of the slot
    int rr = k & 3;
    int kf = a * 2 + (qq >> 1);
    int e  = ((qq & 1) << 2) | rr;
    int lane = ll * 32 + (n & 31);
    int mN = n >> 5;
    size_t dst = ((((size_t)L * 4 + mN) * 8 + kf) * 64 + lane) * 8 + e;
    wpk[dst] = (_Float16)w;     // RNE
}

__global__ __launch_bounds__(512, 2) void mlp_fused(
    const float* __restrict__ x,   const float* __restrict__ W1,
    const float* __restrict__ b1,  const float* __restrict__ bs,
    const float* __restrict__ W17, const float* __restrict__ b17,
    const _Float16* __restrict__ wpk, float* __restrict__ out)
{
    __shared__ __align__(16) _Float16 wbuf[2][16384];   // 2 x 32 KB

    const int tid  = threadIdx.x;
    const int lane = tid & 63;
    const int wid  = tid >> 6;          // 0..7
    const int l5   = lane >> 5;         // 0..1
    const int c31  = lane & 31;
    const int pbase = blockIdx.x * 512 + wid * 64;   // wave owns 64 points

    auto stage = [&](int L, int buf) {
        const _Float16* src = wpk + (size_t)L * 16384;
#pragma unroll
        for (int i = 0; i < 4; ++i) {
            int off = (i * 8 + wid) * 512;   // fp16 elems, wave-uniform
            __builtin_amdgcn_global_load_lds(
                (const __attribute__((address_space(1))) void*)(src + off + lane * 8),
                (__attribute__((address_space(3))) void*)(&wbuf[buf][off]),
                16, 0, 0);
        }
    };

    stage(0, 0);   // overlap with fc1

    // ---- fc1: per-lane, 2 point-tiles x its 64 sigma-slots ----
    half8 bfrag[2][8];   // [point-tile nP][kf] : B-fragments = activations
    float x0[2], x1[2];
#pragma unroll
    for (int nP = 0; nP < 2; ++nP) {
        int p = pbase + nP * 32 + c31;
        floatx2 xv = *(const floatx2*)&x[2 * p];
        x0[nP] = xv[0]; x1[nP] = xv[1];
    }
#pragma unroll
    for (int kf = 0; kf < 8; ++kf) {
#pragma unroll
        for (int eh = 0; eh < 2; ++eh) {
            int nb = (kf >> 1) * 32 + (((kf & 1) << 1) | eh) * 8 + l5 * 4;
            floatx4 wa = *(const floatx4*)&W1[nb];
            floatx4 wb = *(const floatx4*)&W1[128 + nb];
            floatx4 bb = *(const floatx4*)&b1[nb];
#pragma unroll
            for (int nP = 0; nP < 2; ++nP)
#pragma unroll
                for (int r = 0; r < 4; ++r) {
                    float h = fmaf(x0[nP], wa[r], fmaf(x1[nP], wb[r], bb[r]));
                    bfrag[nP][kf][eh * 4 + r] = (_Float16)fmaxf(h, 0.0f);
                }
        }
    }
    __syncthreads();   // wbuf[0] staged (syncthreads drains vmcnt)

    int cur = 0;
    for (int L = 0; L < NLAYER; ++L) {
        if (L + 1 < NLAYER) stage(L + 1, cur ^ 1);

        floatx16 acc[2][4];   // [nP][mN]
#pragma unroll
        for (int nP = 0; nP < 2; ++nP)
#pragma unroll
            for (int mN = 0; mN < 4; ++mN)
#pragma unroll
                for (int e = 0; e < 16; ++e) acc[nP][mN][e] = 0.0f;

#pragma unroll
        for (int mN = 0; mN < 4; ++mN)
#pragma unroll
            for (int kf = 0; kf < 8; ++kf) {
                half8 wf = *(const half8*)&wbuf[cur][(((mN * 8) + kf) * 64 + lane) * 8];
                acc[0][mN] = __builtin_amdgcn_mfma_f32_32x32x16_f16(wf, bfrag[0][kf], acc[0][mN], 0, 0, 0);
                acc[1][mN] = __builtin_amdgcn_mfma_f32_32x32x16_f16(wf, bfrag[1][kf], acc[1][mN], 0, 0, 0);
            }

        // epilogue: bias + relu + cvt, straight into next layer's B-frags
#pragma unroll
        for (int mN = 0; mN < 4; ++mN)
#pragma unroll
            for (int q = 0; q < 4; ++q) {
                floatx4 bb = *(const floatx4*)&bs[L * 128 + mN * 32 + q * 8 + l5 * 4];
#pragma unroll
                for (int nP = 0; nP < 2; ++nP)
#pragma unroll
                    for (int r = 0; r < 4; ++r) {
                        float f = fmaxf(acc[nP][mN][q * 4 + r] + bb[r], 0.0f);
                        bfrag[nP][mN * 2 + (q >> 1)][((q & 1) << 2) | r] = (_Float16)f;
                    }
            }
        __syncthreads();   // all waves done reading wbuf[cur]; next stage landed
        cur ^= 1;
    }

    // ---- fc17: per-lane partial dot over its 64 neurons, xor-32 reduce ----
    float s[2] = {0.0f, 0.0f};
#pragma unroll
    for (int kf = 0; kf < 8; ++kf) {
#pragma unroll
        for (int eh = 0; eh < 2; ++eh) {
            int nb = (kf >> 1) * 32 + (((kf & 1) << 1) | eh) * 8 + l5 * 4;
            floatx4 w4 = *(const floatx4*)&W17[nb];
#pragma unroll
            for (int nP = 0; nP < 2; ++nP)
#pragma unroll
                for (int r = 0; r < 4; ++r)
                    s[nP] = fmaf((float)bfrag[nP][kf][eh * 4 + r], w4[r], s[nP]);
        }
    }
    s[0] += __shfl_xor(s[0], 32);
    s[1] += __shfl_xor(s[1], 32);
    out[pbase + l5 * 32 + c31] = (l5 ? s[1] : s[0]) + b17[0];
}

extern "C" void kernel_launch(void* const* d_in, const int* in_sizes, int n_in,
                              void* d_out, int out_size, void* d_ws, size_t ws_size,
                              hipStream_t stream) {
    const float* x   = (const float*)d_in[0];
    const float* W1  = (const float*)d_in[1];
    const float* b1  = (const float*)d_in[2];
    const float* Ws  = (const float*)d_in[3];
    const float* bs  = (const float*)d_in[4];
    const float* W17 = (const float*)d_in[5];
    const float* b17 = (const float*)d_in[6];
    float* out = (float*)d_out;
    _Float16* wpk = (_Float16*)d_ws;   // 480 KB

    pack_weights<<<960, 256, 0, stream>>>(Ws, wpk);
    mlp_fused<<<2048, 512, 0, stream>>>(x, W1, b1, bs, W17, b17, wpk, out);
}